// Round 4
// baseline (157.535 us; speedup 1.0000x reference)
//
#include <hip/hip_runtime.h>
#include <hip/hip_bf16.h>
#include <stdint.h>

// Problem constants (B=8, S=2048, E=1024, H=128, DK=8)
#define M_DIM 16384   // B*S
#define N_DIM 1024    // E (output features)
#define K_DIM 1024    // E (reduction)

typedef __attribute__((ext_vector_type(8))) short short8;
typedef __attribute__((ext_vector_type(16))) float f32x16;

// async global->LDS, 16B per lane. LDS dest must be wave-uniform base + lane*16.
#define GLD_LDS(g, l) __builtin_amdgcn_global_load_lds( \
    (const __attribute__((address_space(1))) unsigned int*)(g), \
    (__attribute__((address_space(3))) unsigned int*)(l), 16, 0, 0)

__device__ __forceinline__ unsigned short f2bf(float f) {
  union { float f; unsigned int u; } v;
  v.f = f;
  unsigned int u = v.u + 0x7FFFu + ((v.u >> 16) & 1u);  // RNE
  return (unsigned short)(u >> 16);
}

// Fused prep, lane-contiguous: block owns 2048 contiguous elems (2 K-rows).
// Lane t loads float4 at byte offset t*16 (perfect wave coalescing, fixes the
// r3 stride-32B pattern), theta float4 at t*4 loaded once (row phase == 0 mod
// 1024), ushort4 stores. Blocks [0,8192): A = bf16(cos(x+theta)); [8192,8704): W cast.
#define PREP_A_BLOCKS (M_DIM * K_DIM / 2048)   // 8192
#define PREP_W_BLOCKS (N_DIM * K_DIM / 2048)   // 512
__global__ __launch_bounds__(256) void prep_all(const float* __restrict__ x,
                                                const float* __restrict__ theta,
                                                const float* __restrict__ W,
                                                unsigned short* __restrict__ A,
                                                unsigned short* __restrict__ Wb) {
  const int tid = threadIdx.x;
  if (blockIdx.x < PREP_A_BLOCKS) {
    const long base = (long)blockIdx.x * 2048;
    const float4 t = *(const float4*)(theta + tid * 4);
#pragma unroll
    for (int p = 0; p < 2; ++p) {
      const long i = base + p * 1024 + tid * 4;
      const float4 xv = *(const float4*)(x + i);
      ushort4 o;
      o.x = f2bf(__cosf(xv.x + t.x));
      o.y = f2bf(__cosf(xv.y + t.y));
      o.z = f2bf(__cosf(xv.z + t.z));
      o.w = f2bf(__cosf(xv.w + t.w));
      *(ushort4*)(A + i) = o;
    }
  } else {
    const long base = (long)(blockIdx.x - PREP_A_BLOCKS) * 2048;
#pragma unroll
    for (int p = 0; p < 2; ++p) {
      const long i = base + p * 1024 + tid * 4;
      const float4 wv = *(const float4*)(W + i);
      ushort4 o;
      o.x = f2bf(wv.x);
      o.y = f2bf(wv.y);
      o.z = f2bf(wv.z);
      o.w = f2bf(wv.w);
      *(ushort4*)(Wb + i) = o;
    }
  }
}

// C[m,n] = sum_k A[m,k]*Bt[n,k] + bias[n].  A:[M,K] bf16, Bt:[N,K] bf16, C:[M,N] f32.
// 128x128 tile, BK=64, 4 waves of 64x64, 32x32x16 bf16 MFMA (2x2 frags/wave;
// 2382 TF pipe vs 2075 for 16x16 — m119), global_load_lds width=16 staging,
// XOR chunk swizzle (conflicts=0, r2), XCD-banded block remap (FETCH 133->33 MB, r3).
// A-frag: m=lane&31, k=(lane>>5)*8+j. C/D: col=lane&31,
// row=(reg&3)+8*(reg>>2)+4*(lane>>5) (m74/m101-measured).
__global__ __launch_bounds__(256) void gemm_bt(const unsigned short* __restrict__ A,
                                               const unsigned short* __restrict__ Bt,
                                               const float* __restrict__ bias,
                                               float* __restrict__ C) {
  constexpr int BM = 128, BN = 128, BK = 64;
  __shared__ unsigned short As[BM * BK];  // 16 KB
  __shared__ unsigned short Bs[BN * BK];  // 16 KB
  const int tid = threadIdx.x;

  const int L = blockIdx.y * 8 + blockIdx.x;  // linear dispatch id
  const int bx = (L >> 3) & 7;                // N-tile 0..7
  const int by = (L & 7) * 16 + (L >> 6);     // M-tile 0..127, banded per XCD
  const int m0 = by * BM;
  const int n0 = bx * BN;

  const int lane = tid & 63;
  const int wave = tid >> 6;
  const int wm = (wave >> 1) * 64;  // wave tile origin in M
  const int wn = (wave & 1) * 64;   // wave tile origin in N

  f32x16 acc[2][2] = {};

  // Staging: LDS slot d = i*256 + tid holds global chunk (row = d>>3,
  // c = (d&7) ^ (row&7)); (d>>3)&7 == (tid>>3)&7 for all i.
  const int srow = tid >> 3;                         // 0..31
  const int scol = ((tid & 7) ^ (srow & 7)) * 8;     // swizzled source column
  const unsigned short* Ag = A + (long)(m0 + srow) * K_DIM + scol;
  const unsigned short* Bg = Bt + (long)(n0 + srow) * K_DIM + scol;
  unsigned short* Asd = As + tid * 8;
  unsigned short* Bsd = Bs + tid * 8;

  const int fr = lane & 31;        // fragment row (m or n within 32-tile)
  const int kh = (lane >> 5) * 8;  // k-offset of this lane half

  for (int k0 = 0; k0 < K_DIM; k0 += BK) {
    __syncthreads();  // all waves done reading previous tile
#pragma unroll
    for (int i = 0; i < 4; ++i)
      GLD_LDS(Ag + (long)i * 32 * K_DIM, Asd + i * 2048);
#pragma unroll
    for (int i = 0; i < 4; ++i)
      GLD_LDS(Bg + (long)i * 32 * K_DIM, Bsd + i * 2048);
    Ag += BK;
    Bg += BK;
    __syncthreads();  // vmcnt(0) drain -> LDS ready

#pragma unroll
    for (int ks = 0; ks < 4; ++ks) {  // 4 k-steps of 16 per BK=64
      const int c = (ks * 16 + kh) >> 3;  // chunk column 0..7
      short8 af[2], bf[2];
#pragma unroll
      for (int i = 0; i < 2; ++i) {
        const int r = wm + i * 32 + fr;
        af[i] = *(const short8*)(As + r * BK + (c ^ (r & 7)) * 8);
      }
#pragma unroll
      for (int j = 0; j < 2; ++j) {
        const int r = wn + j * 32 + fr;
        bf[j] = *(const short8*)(Bs + r * BK + (c ^ (r & 7)) * 8);
      }
#pragma unroll
      for (int i = 0; i < 2; ++i)
#pragma unroll
        for (int j = 0; j < 2; ++j)
          acc[i][j] = __builtin_amdgcn_mfma_f32_32x32x16_bf16(af[i], bf[j], acc[i][j], 0, 0, 0);
    }
  }

  // Epilogue: C/D col=lane&31, row=(reg&3)+8*(reg>>2)+4*(lane>>5).
  const int cn = lane & 31;
  const int rbase = (lane >> 5) * 4;
#pragma unroll
  for (int j = 0; j < 2; ++j) {
    const int n = n0 + wn + j * 32 + cn;
    const float bv = bias[n];
#pragma unroll
    for (int i = 0; i < 2; ++i) {
      const long mrow = (long)(m0 + wm + i * 32 + rbase);
#pragma unroll
      for (int r = 0; r < 16; ++r) {
        const long row = mrow + (r & 3) + 8 * (r >> 2);
        C[row * N_DIM + n] = acc[i][j][r] + bv;
      }
    }
  }
}

extern "C" void kernel_launch(void* const* d_in, const int* in_sizes, int n_in,
                              void* d_out, int out_size, void* d_ws, size_t ws_size,
                              hipStream_t stream) {
  const float* x = (const float*)d_in[0];      // [8,2048,1024]
  const float* theta = (const float*)d_in[1];  // [128,8] -> flat 1024
  const float* W = (const float*)d_in[2];      // [1024,1024]
  const float* b = (const float*)d_in[3];      // [1024]
  float* out = (float*)d_out;                  // [8,2048,1024] f32

  unsigned short* Abf = (unsigned short*)d_ws;                   // 33.5 MB
  unsigned short* Wbf = Abf + (size_t)M_DIM * K_DIM;             // +2 MB

  hipLaunchKernelGGL(prep_all, dim3(PREP_A_BLOCKS + PREP_W_BLOCKS), dim3(256), 0,
                     stream, x, theta, W, Abf, Wbf);
  hipLaunchKernelGGL(gemm_bt, dim3(N_DIM / 128, M_DIM / 128), dim3(256), 0, stream,
                     Abf, Wbf, b, out);
}